// Round 4
// baseline (285.652 us; speedup 1.0000x reference)
//
#include <hip/hip_runtime.h>
#include <hip/hip_cooperative_groups.h>

namespace cg = cooperative_groups;

#define P_IDS 512
#define DIM 8
#define QMIN 0.01f
#define REP 10.0f
#define CHUNK 64               // particles per phase-C tile
#define NCHUNK (P_IDS / CHUNK) // 8
#define HPT 4                  // hits per thread in phase C
#define HB (256 * HPT)         // 1024 hits per phase-C tile

typedef unsigned long long ull;

// Single cooperative kernel: A) per-block segmented argmax of q into partial
// key tables; B) reduce tables -> (q_alpha, ||x_alpha||^2, x_alpha); C) dense
// N x P potential sweep. grid.sync() provides the cross-XCD release/acquire
// (agent-scope fence -> L2 writeback+invalidate), replacing kernel boundaries.
__launch_bounds__(256, 4)
__global__ void fused_kernel(const float* __restrict__ beta,
                             const float* __restrict__ x,
                             const int* __restrict__ pid,
                             float* __restrict__ q,
                             ull* __restrict__ tables,
                             float2* __restrict__ meta,
                             float* __restrict__ x_alpha,
                             float* __restrict__ out,
                             int n, int a_blocks, int tiles) {
    cg::grid_group grid = cg::this_grid();
    __shared__ ull    s_keys[P_IDS];      // 4 KB  (phase A)
    __shared__ ull    s_kred[4];          //       (phase B)
    __shared__ float  s_xa[CHUNK * DIM];  // 2 KB  (phase C)
    __shared__ float2 s_meta[CHUNK];      // 512 B (phase C)
    __shared__ float  s_red[4];

    const int b   = blockIdx.x;
    const int tid = threadIdx.x;

    // ---------------- Phase A: q + per-block argmax tables -----------------
    // key = qbits<<32 | ~i : order-preserving for q>0, min-index on q ties.
    if (b < a_blocks) {
        s_keys[tid] = 0ULL;
        s_keys[tid + 256] = 0ULL;
        __syncthreads();
        int i = b * 256 + tid;
        if (i < n) {
            float bt = beta[i];
            float at = 0.5f * logf((1.0f + bt) / (1.0f - bt));   // arctanh
            float qv = fmaf(at, at, QMIN);
            q[i] = qv;
            ull key = ((ull)__float_as_uint(qv) << 32) |
                      (ull)(unsigned int)(~(unsigned int)i);
            atomicMax(&s_keys[pid[i]], key);
        }
        __syncthreads();
        ull* dst = tables + (size_t)b * P_IDS;
        dst[tid] = s_keys[tid];
        dst[tid + 256] = s_keys[tid + 256];
    }
    grid.sync();

    // ---------------- Phase B: reduce tables, decode alpha -----------------
    if (b < P_IDS) {
        int p = b;
        ull k = 0ULL;
        for (int t = tid; t < a_blocks; t += 256) {
            ull v = tables[(size_t)t * P_IDS + p];
            k = (v > k) ? v : k;
        }
#pragma unroll
        for (int off = 32; off > 0; off >>= 1) {
            ull o = __shfl_down(k, off, 64);
            k = (o > k) ? o : k;
        }
        if ((tid & 63) == 0) s_kred[tid >> 6] = k;
        __syncthreads();
        if (tid == 0) {
            k = s_kred[0];
            k = (s_kred[1] > k) ? s_kred[1] : k;
            k = (s_kred[2] > k) ? s_kred[2] : k;
            k = (s_kred[3] > k) ? s_kred[3] : k;
            bool valid = (k != 0ULL) && (p != 0);
            float qa = valid ? __uint_as_float((unsigned int)(k >> 32)) : 0.0f;
            int idx = valid ? (int)(~(unsigned int)(k & 0xFFFFFFFFull)) : 0;
            float4 a0 = ((const float4*)x)[idx * 2];
            float4 a1 = ((const float4*)x)[idx * 2 + 1];
            float xa2 = a0.x * a0.x;
            xa2 = fmaf(a0.y, a0.y, xa2); xa2 = fmaf(a0.z, a0.z, xa2);
            xa2 = fmaf(a0.w, a0.w, xa2); xa2 = fmaf(a1.x, a1.x, xa2);
            xa2 = fmaf(a1.y, a1.y, xa2); xa2 = fmaf(a1.z, a1.z, xa2);
            xa2 = fmaf(a1.w, a1.w, xa2);
            ((float4*)x_alpha)[p * 2] = a0;
            ((float4*)x_alpha)[p * 2 + 1] = a1;
            meta[p] = make_float2(qa, xa2);
            if (p == 0) out[0] = 0.0f;
        }
    }
    grid.sync();

    // ---------------- Phase C: dense sweep (tile = 1024 hits x 64 pids) ----
    if (b < tiles) {
        int chunk = b & (NCHUNK - 1);
        int hb    = b / NCHUNK;
        int p0    = chunk * CHUNK;
        if (tid < CHUNK * DIM / 4)
            ((float4*)s_xa)[tid] = ((const float4*)(x_alpha + p0 * DIM))[tid];
        if (tid < CHUNK) s_meta[tid] = meta[p0 + tid];
        __syncthreads();

        float xi[HPT][DIM], xi2[HPT], qi[HPT], acc[HPT];
        int   myj[HPT];
        int base = hb * HB + tid;
#pragma unroll
        for (int h = 0; h < HPT; ++h) {
            int i = base + h * 256;
            bool act = i < n;
            int ii = act ? i : 0;
            float4 v0 = ((const float4*)x)[ii * 2];
            float4 v1 = ((const float4*)x)[ii * 2 + 1];
            xi[h][0] = v0.x; xi[h][1] = v0.y; xi[h][2] = v0.z; xi[h][3] = v0.w;
            xi[h][4] = v1.x; xi[h][5] = v1.y; xi[h][6] = v1.z; xi[h][7] = v1.w;
            float s = 0.0f;
#pragma unroll
            for (int d = 0; d < DIM; ++d) s = fmaf(xi[h][d], xi[h][d], s);
            xi2[h] = s;
            qi[h]  = act ? q[ii] : 0.0f;        // masks inactive lanes
            myj[h] = act ? (pid[ii] - p0) : -1;
            acc[h] = 0.0f;
        }

        for (int j = 0; j < CHUNK; ++j) {
            float2 m  = s_meta[j];
            float4 a0 = ((const float4*)s_xa)[j * 2];
            float4 a1 = ((const float4*)s_xa)[j * 2 + 1];
            float sq[HPT];
#pragma unroll
            for (int h = 0; h < HPT; ++h) {
                float dot = xi[h][0] * a0.x;
                dot = fmaf(xi[h][1], a0.y, dot); dot = fmaf(xi[h][2], a0.z, dot);
                dot = fmaf(xi[h][3], a0.w, dot); dot = fmaf(xi[h][4], a1.x, dot);
                dot = fmaf(xi[h][5], a1.y, dot); dot = fmaf(xi[h][6], a1.z, dot);
                dot = fmaf(xi[h][7], a1.w, dot);
                sq[h] = fmaxf(fmaf(-2.0f, dot, xi2[h] + m.y), 0.0f);
            }
            float mn = fminf(fminf(sq[0], sq[1]), fminf(sq[2], sq[3]));
            if (__any(mn < 1.0f)) {             // vr == 0 otherwise
#pragma unroll
                for (int h = 0; h < HPT; ++h) {
                    float vr = fmaxf(1.0f - __builtin_amdgcn_sqrtf(sq[h]), 0.0f);
                    acc[h] = fmaf(vr, m.x, acc[h]);
                }
            }
        }

        float partial = 0.0f;
#pragma unroll
        for (int h = 0; h < HPT; ++h) {
            float t = REP * acc[h];             // repulsive, pre-scaled
            int j = myj[h];
            if (j >= 0 && j < CHUNK) {          // own-pair correction
                float2 m = s_meta[j];
                float dot = xi[h][0] * s_xa[j * DIM + 0];
#pragma unroll
                for (int d = 1; d < DIM; ++d)
                    dot = fmaf(xi[h][d], s_xa[j * DIM + d], dot);
                float sq = fmaxf(fmaf(-2.0f, dot, xi2[h] + m.y), 0.0f);
                float vr = fmaxf(1.0f - __builtin_amdgcn_sqrtf(sq), 0.0f);
                t += m.x * (sq - REP * vr);     // swap repulsive -> attractive
            }
            partial = fmaf(qi[h], t, partial);
        }

#pragma unroll
        for (int off = 32; off > 0; off >>= 1)
            partial += __shfl_down(partial, off, 64);
        if ((tid & 63) == 0) s_red[tid >> 6] = partial;
        __syncthreads();
        if (tid == 0)
            atomicAdd(out, (s_red[0] + s_red[1] + s_red[2] + s_red[3]) / (float)n);
    }
}

extern "C" void kernel_launch(void* const* d_in, const int* in_sizes, int n_in,
                              void* d_out, int out_size, void* d_ws, size_t ws_size,
                              hipStream_t stream) {
    int n = in_sizes[0];
    const float* beta = (const float*)d_in[1];
    const float* x    = (const float*)d_in[2];
    const int*   pid  = (const int*)d_in[4];
    float* out = (float*)d_out;

    int a_blocks = (n + 255) / 256;            // 392
    int tiles    = ((n + HB - 1) / HB) * NCHUNK; // 98*8 = 784
    int grid     = tiles > P_IDS ? tiles : P_IDS;
    if (grid < a_blocks) grid = a_blocks;

    char* ws = (char*)d_ws;
    size_t tab_bytes = ((size_t)a_blocks * P_IDS * sizeof(ull) + 255) & ~(size_t)255;
    size_t q_bytes   = (((size_t)n * 4) + 255) & ~(size_t)255;
    ull*    tables  = (ull*)ws;
    float*  q       = (float*)(ws + tab_bytes);
    float2* meta    = (float2*)(ws + tab_bytes + q_bytes);
    float*  x_alpha = (float*)(ws + tab_bytes + q_bytes + P_IDS * sizeof(float2));

    void* args[] = {(void*)&beta, (void*)&x, (void*)&pid, (void*)&q,
                    (void*)&tables, (void*)&meta, (void*)&x_alpha, (void*)&out,
                    (void*)&n, (void*)&a_blocks, (void*)&tiles};
    hipLaunchCooperativeKernel((void*)fused_kernel, dim3(grid), dim3(256),
                               args, 0, stream);
}

// Round 5
// 97.611 us; speedup vs baseline: 2.9264x; 2.9264x over previous
//
#include <hip/hip_runtime.h>

#define P_IDS 512
#define DIM 8
#define QMIN 0.01f
#define REP 10.0f
#define TBLS 64                // stage-A blocks == partial key tables
#define CHUNK 64               // particles per loss-block chunk
#define NCHUNK (P_IDS / CHUNK) // 8
#define HPT 4                  // hits per thread in the sweep
#define HB (256 * HPT)         // 1024 hits per loss block

typedef unsigned long long ull;

// Stage A: q_i = arctanh(beta_i)^2 + QMIN; per-block segmented argmax into LDS
// (key = qbits<<32 | ~i -> order-preserving for q>0, min-index on q ties).
// 64 blocks, grid-stride (~6 hits/thread); tables[t][p] row-major so each
// block's flush is one contiguous 4 KB write. Block 0 zeroes the accumulator.
__launch_bounds__(256)
__global__ void stageA_kernel(const float* __restrict__ beta,
                              const int* __restrict__ pid,
                              float* __restrict__ q_out,
                              ull* __restrict__ tables,
                              float* __restrict__ out,
                              int n) {
    __shared__ ull s_keys[P_IDS];
    s_keys[threadIdx.x] = 0ULL;
    s_keys[threadIdx.x + 256] = 0ULL;
    __syncthreads();
    for (int i = blockIdx.x * 256 + threadIdx.x; i < n; i += TBLS * 256) {
        float b = beta[i];
        float at = 0.5f * logf((1.0f + b) / (1.0f - b));   // arctanh
        float qv = fmaf(at, at, QMIN);
        q_out[i] = qv;
        ull key = ((ull)__float_as_uint(qv) << 32) |
                  (ull)(unsigned int)(~(unsigned int)i);
        atomicMax(&s_keys[pid[i]], key);
    }
    __syncthreads();
    ull* dst = tables + (size_t)blockIdx.x * P_IDS;
    dst[threadIdx.x] = s_keys[threadIdx.x];
    dst[threadIdx.x + 256] = s_keys[threadIdx.x + 256];
    if (blockIdx.x == 0 && threadIdx.x == 0) out[0] = 0.0f;
}

// Loss: block = 1024 hits x one 64-particle chunk. Prologue reduces this
// chunk's slice of the 64 partial tables (coalesced 512 B row reads), decodes
// alpha hits into LDS. Sweep: repulsive-only dense loop (sqrt skipped when the
// whole wave has sq >= 1), own-pair attractive correction post-loop.
__launch_bounds__(256)
__global__ void loss_kernel(const float* __restrict__ x,
                            const float* __restrict__ q,
                            const int* __restrict__ pid,
                            const ull* __restrict__ tables,
                            float* __restrict__ out,
                            int n) {
    __shared__ ull    s_part[4][CHUNK];    // 2 KB
    __shared__ float  s_xa[CHUNK * DIM];   // 2 KB
    __shared__ float2 s_meta[CHUNK];       // 512 B
    __shared__ float  s_red[4];

    const int tid  = threadIdx.x;
    const int wave = tid >> 6, lane = tid & 63;
    const int chunk = blockIdx.x & (NCHUNK - 1);
    const int hb    = blockIdx.x / NCHUNK;
    const int p0    = chunk * CHUNK;

    // ---- reduce the 64 partial tables for this chunk's 64 particles ----
    ull k = 0ULL;
#pragma unroll
    for (int t = wave; t < TBLS; t += 4) {
        ull v = tables[(size_t)t * P_IDS + p0 + lane];   // 512 B coalesced row
        k = (v > k) ? v : k;
    }
    s_part[wave][lane] = k;
    __syncthreads();
    if (tid < CHUNK) {
        k = s_part[0][tid];
        ull v1 = s_part[1][tid], v2 = s_part[2][tid], v3 = s_part[3][tid];
        k = (v1 > k) ? v1 : k; k = (v2 > k) ? v2 : k; k = (v3 > k) ? v3 : k;
        bool valid = (k != 0ULL) && ((p0 + tid) != 0);
        float qa = valid ? __uint_as_float((unsigned int)(k >> 32)) : 0.0f;
        int idx = valid ? (int)(~(unsigned int)(k & 0xFFFFFFFFull)) : 0;
        float4 a0 = ((const float4*)x)[idx * 2];
        float4 a1 = ((const float4*)x)[idx * 2 + 1];
        float xa2 = a0.x * a0.x;
        xa2 = fmaf(a0.y, a0.y, xa2); xa2 = fmaf(a0.z, a0.z, xa2);
        xa2 = fmaf(a0.w, a0.w, xa2); xa2 = fmaf(a1.x, a1.x, xa2);
        xa2 = fmaf(a1.y, a1.y, xa2); xa2 = fmaf(a1.z, a1.z, xa2);
        xa2 = fmaf(a1.w, a1.w, xa2);
        ((float4*)s_xa)[tid * 2] = a0;
        ((float4*)s_xa)[tid * 2 + 1] = a1;
        s_meta[tid] = make_float2(qa, xa2);
    }
    __syncthreads();

    // ---- dense sweep ----
    float xi[HPT][DIM], xi2[HPT], qi[HPT], acc[HPT];
    int   myj[HPT];
    int base = hb * HB + tid;
#pragma unroll
    for (int h = 0; h < HPT; ++h) {
        int i = base + h * 256;
        bool act = i < n;
        int ii = act ? i : 0;
        float4 v0 = ((const float4*)x)[ii * 2];
        float4 v1 = ((const float4*)x)[ii * 2 + 1];
        xi[h][0] = v0.x; xi[h][1] = v0.y; xi[h][2] = v0.z; xi[h][3] = v0.w;
        xi[h][4] = v1.x; xi[h][5] = v1.y; xi[h][6] = v1.z; xi[h][7] = v1.w;
        float s = 0.0f;
#pragma unroll
        for (int d = 0; d < DIM; ++d) s = fmaf(xi[h][d], xi[h][d], s);
        xi2[h] = s;
        qi[h]  = act ? q[ii] : 0.0f;        // masks inactive lanes
        myj[h] = act ? (pid[ii] - p0) : -1;
        acc[h] = 0.0f;
    }

    for (int j = 0; j < CHUNK; ++j) {
        float2 m  = s_meta[j];
        float4 a0 = ((const float4*)s_xa)[j * 2];
        float4 a1 = ((const float4*)s_xa)[j * 2 + 1];
        float sq[HPT];
#pragma unroll
        for (int h = 0; h < HPT; ++h) {
            float dot = xi[h][0] * a0.x;
            dot = fmaf(xi[h][1], a0.y, dot); dot = fmaf(xi[h][2], a0.z, dot);
            dot = fmaf(xi[h][3], a0.w, dot); dot = fmaf(xi[h][4], a1.x, dot);
            dot = fmaf(xi[h][5], a1.y, dot); dot = fmaf(xi[h][6], a1.z, dot);
            dot = fmaf(xi[h][7], a1.w, dot);
            sq[h] = fmaxf(fmaf(-2.0f, dot, xi2[h] + m.y), 0.0f);
        }
        float mn = fminf(fminf(sq[0], sq[1]), fminf(sq[2], sq[3]));
        if (__any(mn < 1.0f)) {             // vr == 0 for all pairs otherwise
#pragma unroll
            for (int h = 0; h < HPT; ++h) {
                float vr = fmaxf(1.0f - __builtin_amdgcn_sqrtf(sq[h]), 0.0f);
                acc[h] = fmaf(vr, m.x, acc[h]);
            }
        }
    }

    float partial = 0.0f;
#pragma unroll
    for (int h = 0; h < HPT; ++h) {
        float t = REP * acc[h];             // repulsive, pre-scaled
        int j = myj[h];
        if (j >= 0 && j < CHUNK) {          // own-pair correction
            float2 m = s_meta[j];
            float dot = xi[h][0] * s_xa[j * DIM + 0];
#pragma unroll
            for (int d = 1; d < DIM; ++d)
                dot = fmaf(xi[h][d], s_xa[j * DIM + d], dot);
            float sq = fmaxf(fmaf(-2.0f, dot, xi2[h] + m.y), 0.0f);
            float vr = fmaxf(1.0f - __builtin_amdgcn_sqrtf(sq), 0.0f);
            t += m.x * (sq - REP * vr);     // swap repulsive -> attractive
        }
        partial = fmaf(qi[h], t, partial);
    }

#pragma unroll
    for (int off = 32; off > 0; off >>= 1)
        partial += __shfl_down(partial, off, 64);
    if ((tid & 63) == 0) s_red[tid >> 6] = partial;
    __syncthreads();
    if (tid == 0)
        atomicAdd(out, (s_red[0] + s_red[1] + s_red[2] + s_red[3]) / (float)n);
}

extern "C" void kernel_launch(void* const* d_in, const int* in_sizes, int n_in,
                              void* d_out, int out_size, void* d_ws, size_t ws_size,
                              hipStream_t stream) {
    int n = in_sizes[0];
    const float* beta = (const float*)d_in[1];
    const float* x    = (const float*)d_in[2];
    const int*   pid  = (const int*)d_in[4];
    float* out = (float*)d_out;

    char* ws = (char*)d_ws;
    size_t tab_bytes = ((size_t)TBLS * P_IDS * sizeof(ull) + 255) & ~(size_t)255;
    ull*   tables = (ull*)ws;
    float* q      = (float*)(ws + tab_bytes);

    stageA_kernel<<<TBLS, 256, 0, stream>>>(beta, pid, q, tables, out, n);
    int hit_blocks = (n + HB - 1) / HB;                        // 98
    loss_kernel<<<hit_blocks * NCHUNK, 256, 0, stream>>>(x, q, pid, tables, out, n);
}